// Round 15
// baseline (319.759 us; speedup 1.0000x reference)
//
#include <hip/hip_runtime.h>
#include <stdint.h>

#define IN_F   4096
#define OUT_F  4096
#define M_TOT  8192
#define KDIM   4096

typedef float          f32x4   __attribute__((ext_vector_type(4)));
typedef float          f32x16  __attribute__((ext_vector_type(16)));
typedef int            i32x4   __attribute__((ext_vector_type(4)));
typedef unsigned short u16x8   __attribute__((ext_vector_type(8)));
typedef __bf16         bf16x8  __attribute__((ext_vector_type(8)));

// round-to-nearest-even f32 -> bf16
__device__ __forceinline__ unsigned short f2bf(float f) {
  uint32_t u = __builtin_bit_cast(uint32_t, f);
  u = (u + 0x7FFFu + ((u >> 16) & 1u)) >> 16;
  return (unsigned short)u;
}
__device__ __forceinline__ float bf2f(unsigned short s) {
  return __builtin_bit_cast(float, (uint32_t)s << 16);
}

// async global->LDS; dest = wave-uniform base, HW adds lane*16
__device__ __forceinline__ void gld_lds16(const void* g, void* l) {
  __builtin_amdgcn_global_load_lds((const __attribute__((address_space(1))) void*)g,
                                   (__attribute__((address_space(3))) void*)l,
                                   16, 0, 0);
}

// ---------- kernel 1: x (fp32) -> bf16, 8 elems/thread ----------
__global__ __launch_bounds__(256) void k_xcast(const f32x4* __restrict__ x,
                                               u16x8* __restrict__ xb) {
  int t = blockIdx.x * 256 + threadIdx.x;
  f32x4 a = x[2 * t];
  f32x4 b = x[2 * t + 1];
  u16x8 o;
  o[0] = f2bf(a[0]); o[1] = f2bf(a[1]); o[2] = f2bf(a[2]); o[3] = f2bf(a[3]);
  o[4] = f2bf(b[0]); o[5] = f2bf(b[1]); o[6] = f2bf(b[2]); o[7] = f2bf(b[3]);
  xb[t] = o;
}

// ---------- kernel 2: L[o][i] = bf16( 2.0 * sum_r A[i][r]*B[r][o] ) ----------
__global__ __launch_bounds__(256) void k_lora(const float* __restrict__ A,   // [IN_F][16]
                                              const float* __restrict__ Bm,  // [16][OUT_F]
                                              unsigned short* __restrict__ L) { // [OUT_F][IN_F] bf16
  __shared__ float sB[16][64];
  const int ib = blockIdx.x * 256;
  const int ob = blockIdx.y * 64;
  const int t  = threadIdx.x;
  for (int j = 0; j < 4; ++j) {
    int idx = t + j * 256;
    int r = idx >> 6, oc = idx & 63;
    sB[r][oc] = Bm[r * OUT_F + ob + oc];
  }
  float a[16];
  const f32x4* Ap = (const f32x4*)(A + (size_t)(ib + t) * 16);
  #pragma unroll
  for (int j = 0; j < 4; ++j) {
    f32x4 v = Ap[j];
    a[4*j+0] = v[0]; a[4*j+1] = v[1]; a[4*j+2] = v[2]; a[4*j+3] = v[3];
  }
  __syncthreads();
  unsigned short* Lp = L + (size_t)ob * IN_F + ib + t;
  #pragma unroll 4
  for (int oc = 0; oc < 64; ++oc) {
    float acc = 0.f;
    #pragma unroll
    for (int r = 0; r < 16; ++r) acc += a[r] * sB[r][oc];
    Lp[(size_t)oc * IN_F] = f2bf(acc * 2.0f);   // LORA_SCALE = 32/16
  }
}

// ---------- kernel 3: dequant INT4 + merge L -> Wc bf16 [OUT_F][IN_F] ----------
__global__ __launch_bounds__(256) void k_dequant(const int* __restrict__ idx,
                                                 const float* __restrict__ cb,
                                                 const float* __restrict__ scales,
                                                 const unsigned short* __restrict__ L,
                                                 unsigned short* __restrict__ Wc) {
  __shared__ float scb[16];
  const int t = blockIdx.x * 256 + threadIdx.x;
  if (threadIdx.x < 16) scb[threadIdx.x] = cb[threadIdx.x];
  __syncthreads();
  i32x4 w = ((const i32x4*)idx)[t];
  float sc = scales[t >> 4];
  u16x8 lw = ((const u16x8*)L)[t];
  u16x8 o;
  #pragma unroll
  for (int j = 0; j < 4; ++j) {
    int word = w[j];
    float v0 = scb[word & 15] * sc + bf2f(lw[2 * j]);
    float v1 = scb[(word >> 4) & 15] * sc + bf2f(lw[2 * j + 1]);
    o[2 * j]     = f2bf(v0);
    o[2 * j + 1] = f2bf(v1);
  }
  ((u16x8*)Wc)[t] = o;
}

// ---------- kernel 4: 256x256 bf16 GEMM, 4 waves, 32x32x16 MFMA ----------
// C[m][n] = sum_k A[m][k]*B[n][k] + bias[n];  A:[8192][4096], B:[4096][4096] bf16.
// 256 thr = 4 waves (2M x 2N); wave tile 128x128 (4x4 frags of 32x32); BK=64.
// LDS 128 KiB: A buf c at c*32768 (256 rows x 128B), B at 65536+c*32768. XOR-8
// swizzle (slot^(row&7)) via pre-swizzled global source + XOR on read (0-conflict
// measured geometry preserved: distinct rows per lane, slots XOR-spread).
//
// ROUND-15 rationale: six schedule variants pinned at 52-55% because LDS-read issue
// (192 b128/CU-tile, ~2300cyc) ~= MFMA (2486cyc) at 8-wave 16x16. This layout cuts
// A-read redundancy 4x->2x: 128 b128/CU-tile (~1540cyc) vs MFMA ~2070cyc (32x32
// rate is 15% higher than 16x16 per µbench). 1 wave/SIMD: per kstep(K=16), next
// kstep's 8 frag reads issue textually before the 16 MFMAs — compiler counted-lgkm
// hides them under the ~516cyc MFMA cluster. Single VMC0+BARR per tile (R9 pattern).
//
// 32x32x16 operand/C layouts (m74/m101-verified family):
//   A frag: lane&31 = M-row, k = (lane>>5)*8 + j   (bf16x8, 4 VGPR)
//   B frag: lane&31 = N-col, k = (lane>>5)*8 + j   (B^T rows read identically)
//   C/D:    col = lane&31, row = (reg&3) + 8*(reg>>2) + 4*(lane>>5)

#define BARR()  __builtin_amdgcn_s_barrier()
#define SCHB()  __builtin_amdgcn_sched_barrier(0)
#define LGKM0() asm volatile("s_waitcnt lgkmcnt(0)" ::: "memory")
#define VMC0()  asm volatile("s_waitcnt vmcnt(0)" ::: "memory")

// stage K-tile kt into buffer c: 16 gld_lds, 4KB each (256 thr x 16B)
#define STAGE16(kt, c) do {                                                              \
  _Pragma("unroll")                                                                      \
  for (int i = 0; i < 8; ++i)                                                            \
    gld_lds16(Ag + (size_t)(i * 32) * KDIM + (kt) * 64,                                  \
              smem + (c) * 32768 + i * 4096 + ldsw);                                     \
  _Pragma("unroll")                                                                      \
  for (int i = 0; i < 8; ++i)                                                            \
    gld_lds16(Bg + (size_t)(i * 32) * KDIM + (kt) * 64,                                  \
              smem + 65536 + (c) * 32768 + i * 4096 + ldsw);                             \
} while (0)

// read one kstep's fragments (4 A + 4 B) at swizzled byte col CS
#define READK(SA, SB, c, CS) do {                                                        \
  _Pragma("unroll")                                                                      \
  for (int m = 0; m < 4; ++m)                                                            \
    SA[m] = *(const bf16x8*)(smem + (c) * 32768 + rowAb + m * 4096 + (CS));              \
  _Pragma("unroll")                                                                      \
  for (int n = 0; n < 4; ++n)                                                            \
    SB[n] = *(const bf16x8*)(smem + 65536 + (c) * 32768 + rowBb + n * 4096 + (CS));      \
} while (0)

#define MFMAK(SA, SB) do {                                                               \
  __builtin_amdgcn_s_setprio(1);                                                         \
  _Pragma("unroll")                                                                      \
  for (int m = 0; m < 4; ++m)                                                            \
    _Pragma("unroll")                                                                    \
    for (int n = 0; n < 4; ++n)                                                          \
      acc[m][n] = __builtin_amdgcn_mfma_f32_32x32x16_bf16(SA[m], SB[n],                  \
                                                          acc[m][n], 0, 0, 0);          \
  __builtin_amdgcn_s_setprio(0);                                                         \
} while (0)

// Tile t on buf c: stage t+1 -> c^1; ksteps pipelined with 2 frag sets.
// Reads of buf c all consumed by this tile's MFMAs (counted lgkm) -> retired
// before end barrier; stage targets c^1 only (readers drained last tile);
// VMC0 drains the 16 stage loads (issued ~2000cyc earlier) before BARR.
#define TILE7(t_, c_, doStage) do {                                                      \
  if (doStage) STAGE16((t_) + 1, (c_) ^ 1);                                              \
  READK(a0, b0, c_, cs0);                                                                \
  READK(a1, b1, c_, cs1);                                                                \
  MFMAK(a0, b0);                                                                         \
  READK(a0, b0, c_, cs2);                                                                \
  MFMAK(a1, b1);                                                                         \
  READK(a1, b1, c_, cs3);                                                                \
  MFMAK(a0, b0);                                                                         \
  MFMAK(a1, b1);                                                                         \
  VMC0(); BARR(); SCHB();                                                                \
} while (0)

__global__ __launch_bounds__(256, 1) void k_gemm(const unsigned short* __restrict__ A,
                                                 const unsigned short* __restrict__ B,
                                                 const float* __restrict__ bias,
                                                 float* __restrict__ C) {
  __shared__ char smem[131072];
  const int tid  = threadIdx.x;
  const int lane = tid & 63;
  const int wv   = tid >> 6;     // 0..3
  const int wm   = wv >> 1;      // 0..1
  const int wn   = wv & 1;       // 0..1
  const int r32  = lane & 31;
  const int h    = lane >> 5;    // 0..1  k-octet
  const int xr5  = r32 & 7;
  const int cs0 = ((0 + h) ^ xr5) << 4;   // swizzled byte col, kstep 0 (k=0..15)
  const int cs1 = ((2 + h) ^ xr5) << 4;   // kstep 1
  const int cs2 = ((4 + h) ^ xr5) << 4;   // kstep 2
  const int cs3 = ((6 + h) ^ xr5) << 4;   // kstep 3
  const int rowAb = (wm * 128 + r32) * 128;   // byte row base in A tile
  const int rowBb = (wn * 128 + r32) * 128;   // byte row base in B tile
  const int srow = tid >> 3;                  // 0..31 staging row (within 32-row group)
  const int scol = ((tid & 7) ^ ((tid >> 3) & 7)) * 8;  // pre-swizzled global elem col
  const int ldsw = wv * 1024;                 // wave's byte slot per staging call
  const int bm = blockIdx.x;                  // 0..31
  const int bn = blockIdx.y;                  // 0..15

  const unsigned short* Ag = A + (size_t)(bm * 256 + srow) * KDIM + scol;
  const unsigned short* Bg = B + (size_t)(bn * 256 + srow) * KDIM + scol;

  bf16x8 a0[4], a1[4], b0[4], b1[4];
  f32x16 acc[4][4];
  #pragma unroll
  for (int m = 0; m < 4; ++m)
    #pragma unroll
    for (int n = 0; n < 4; ++n)
      #pragma unroll
      for (int j = 0; j < 16; ++j)
        acc[m][n][j] = 0.f;

  // prologue: stage tile 0 into buf0
  STAGE16(0, 0);
  VMC0();
  BARR(); SCHB();

  #pragma unroll 1
  for (int t = 0; t < 62; t += 2) {
    TILE7(t,     0, 1);
    TILE7(t + 1, 1, 1);
  }
  TILE7(62, 0, 1);
  TILE7(63, 1, 0);

  // ---- epilogue: padded-LDS repack + coalesced 128B stores ----
  // eps in buf0 [0,19KB): buf0's last reads = tile 62 (retired before its BARR);
  // last buf0 stage = t61 (drained t61 VMC0). __syncthreads() = real fence.
  // C frag layout: col=lane&31, row=(j&3)+8*(j>>2)+4*h. [32][36] f32 pad:
  // scatter banks (4*row+col)%32 -> 32 distinct per write; gather rows 16B-aligned.
  __syncthreads();
  {
    float* eps = (float*)(smem + wv * 4736);   // [32][36] f32 = 4608B, 16B-aligned slot
    const int row0 = bm * 256 + wm * 128;
    const int col0 = bn * 256 + wn * 128;
    const int gr = lane >> 3;    // 0..7 gather row group
    const int gc = lane & 7;     // 0..7 gather col quad
    f32x4 b4[4];
    #pragma unroll
    for (int n = 0; n < 4; ++n)
      b4[n] = *(const f32x4*)(bias + col0 + n * 32 + gc * 4);
    #pragma unroll
    for (int m = 0; m < 4; ++m) {
      #pragma unroll
      for (int n = 0; n < 4; ++n) {
        #pragma unroll
        for (int j = 0; j < 16; ++j) {
          const int rj = (j & 3) + 8 * (j >> 2) + 4 * h;
          eps[rj * 36 + r32] = acc[m][n][j];
        }
        LGKM0();
        __builtin_amdgcn_sched_barrier(0);
        #pragma unroll
        for (int p = 0; p < 4; ++p) {
          const int row = gr + 8 * p;
          f32x4 v = *(const f32x4*)(eps + row * 36 + gc * 4);
          v[0] += b4[n][0]; v[1] += b4[n][1]; v[2] += b4[n][2]; v[3] += b4[n][3];
          *(f32x4*)(C + (size_t)(row0 + m * 32 + row) * OUT_F + col0 + n * 32 + gc * 4) = v;
        }
        asm volatile("" ::: "memory");   // gather done before next frag's scatter
      }
    }
  }
}

extern "C" void kernel_launch(void* const* d_in, const int* in_sizes, int n_in,
                              void* d_out, int out_size, void* d_ws, size_t ws_size,
                              hipStream_t stream) {
  const float* x    = (const float*)d_in[0];
  const int*   idx  = (const int*)d_in[1];
  const float* cb   = (const float*)d_in[2];
  const float* scl  = (const float*)d_in[3];
  const float* lA   = (const float*)d_in[4];
  const float* lB   = (const float*)d_in[5];
  const float* bias = (const float*)d_in[6];
  float* out = (float*)d_out;

  unsigned short* xb = (unsigned short*)d_ws;
  unsigned short* Wc = (unsigned short*)((char*)d_ws + (size_t)M_TOT * KDIM * 2);
  unsigned short* Lbuf = (unsigned short*)d_out;  // bf16 LoRA scratch; overwritten by k_gemm

  k_xcast<<<16384, 256, 0, stream>>>((const f32x4*)x, (u16x8*)xb);
  k_lora<<<dim3(16, 64), 256, 0, stream>>>(lA, lB, Lbuf);
  k_dequant<<<8192, 256, 0, stream>>>(idx, cb, scl, Lbuf, Wc);
  k_gemm<<<dim3(32, 16), 256, 0, stream>>>(xb, Wc, bias, out);
}

// Round 16
// 280.152 us; speedup vs baseline: 1.1414x; 1.1414x over previous
//
#include <hip/hip_runtime.h>
#include <stdint.h>

#define IN_F   4096
#define OUT_F  4096
#define M_TOT  8192
#define KDIM   4096

typedef float          f32x4  __attribute__((ext_vector_type(4)));
typedef int            i32x4  __attribute__((ext_vector_type(4)));
typedef unsigned short u16x8  __attribute__((ext_vector_type(8)));
typedef __bf16         bf16x8 __attribute__((ext_vector_type(8)));

// round-to-nearest-even f32 -> bf16
__device__ __forceinline__ unsigned short f2bf(float f) {
  uint32_t u = __builtin_bit_cast(uint32_t, f);
  u = (u + 0x7FFFu + ((u >> 16) & 1u)) >> 16;
  return (unsigned short)u;
}
__device__ __forceinline__ float bf2f(unsigned short s) {
  return __builtin_bit_cast(float, (uint32_t)s << 16);
}

// async global->LDS; dest = wave-uniform base, HW adds lane*16
__device__ __forceinline__ void gld_lds16(const void* g, void* l) {
  __builtin_amdgcn_global_load_lds((const __attribute__((address_space(1))) void*)g,
                                   (__attribute__((address_space(3))) void*)l,
                                   16, 0, 0);
}

// ---------- kernel 1: x (fp32) -> bf16, 8 elems/thread ----------
__global__ __launch_bounds__(256) void k_xcast(const f32x4* __restrict__ x,
                                               u16x8* __restrict__ xb) {
  int t = blockIdx.x * 256 + threadIdx.x;
  f32x4 a = x[2 * t];
  f32x4 b = x[2 * t + 1];
  u16x8 o;
  o[0] = f2bf(a[0]); o[1] = f2bf(a[1]); o[2] = f2bf(a[2]); o[3] = f2bf(a[3]);
  o[4] = f2bf(b[0]); o[5] = f2bf(b[1]); o[6] = f2bf(b[2]); o[7] = f2bf(b[3]);
  xb[t] = o;
}

// ---------- kernel 2: L[o][i] = bf16( 2.0 * sum_r A[i][r]*B[r][o] ) ----------
__global__ __launch_bounds__(256) void k_lora(const float* __restrict__ A,   // [IN_F][16]
                                              const float* __restrict__ Bm,  // [16][OUT_F]
                                              unsigned short* __restrict__ L) { // [OUT_F][IN_F] bf16
  __shared__ float sB[16][64];
  const int ib = blockIdx.x * 256;
  const int ob = blockIdx.y * 64;
  const int t  = threadIdx.x;
  for (int j = 0; j < 4; ++j) {
    int idx = t + j * 256;
    int r = idx >> 6, oc = idx & 63;
    sB[r][oc] = Bm[r * OUT_F + ob + oc];
  }
  float a[16];
  const f32x4* Ap = (const f32x4*)(A + (size_t)(ib + t) * 16);
  #pragma unroll
  for (int j = 0; j < 4; ++j) {
    f32x4 v = Ap[j];
    a[4*j+0] = v[0]; a[4*j+1] = v[1]; a[4*j+2] = v[2]; a[4*j+3] = v[3];
  }
  __syncthreads();
  unsigned short* Lp = L + (size_t)ob * IN_F + ib + t;
  #pragma unroll 4
  for (int oc = 0; oc < 64; ++oc) {
    float acc = 0.f;
    #pragma unroll
    for (int r = 0; r < 16; ++r) acc += a[r] * sB[r][oc];
    Lp[(size_t)oc * IN_F] = f2bf(acc * 2.0f);   // LORA_SCALE = 32/16
  }
}

// ---------- kernel 3: dequant INT4 + merge L -> Wc bf16 [OUT_F][IN_F] ----------
__global__ __launch_bounds__(256) void k_dequant(const int* __restrict__ idx,
                                                 const float* __restrict__ cb,
                                                 const float* __restrict__ scales,
                                                 const unsigned short* __restrict__ L,
                                                 unsigned short* __restrict__ Wc) {
  __shared__ float scb[16];
  const int t = blockIdx.x * 256 + threadIdx.x;
  if (threadIdx.x < 16) scb[threadIdx.x] = cb[threadIdx.x];
  __syncthreads();
  i32x4 w = ((const i32x4*)idx)[t];
  float sc = scales[t >> 4];
  u16x8 lw = ((const u16x8*)L)[t];
  u16x8 o;
  #pragma unroll
  for (int j = 0; j < 4; ++j) {
    int word = w[j];
    float v0 = scb[word & 15] * sc + bf2f(lw[2 * j]);
    float v1 = scb[(word >> 4) & 15] * sc + bf2f(lw[2 * j + 1]);
    o[2 * j]     = f2bf(v0);
    o[2 * j + 1] = f2bf(v1);
  }
  ((u16x8*)Wc)[t] = o;
}

// ---------- kernel 4: 256x256 bf16 GEMM (best-measured config, R12) ----------
// C[m][n] = sum_k A[m][k]*B[n][k] + bias[n];  A:[8192][4096] bf16, B:[4096][4096] bf16.
// 512 thr = 8 waves (2M x 4N); wave out 128x64; BK=64; 128 KiB LDS dbuf.
// LDS: A buf c at c*32768 (256 rows x 128B); B buf c at 65536+c*32768. XOR-8 swizzle
// (slot^(row&7)) via pre-swizzled global source + XOR on ds_read — measured 0 conflicts.
// One LGKM0+VMC0+BARR per K-tile; stage targets only buf c^1 (readers retired last
// tile). Measured: k_gemm ~231 µs (1190 TF), MfmaUtil ~55%, FETCH ~197 MB.
// Plateau note: 7 structural variants (phase splits, pipelines, 32x32 shape) all
// land <=55%; binding term is LDS-read issue phase-locked against MFMA by the
// barrier-coupled dbuf. Path beyond is m201's exact interleave / inline-asm K-loop.

#define BARR()  __builtin_amdgcn_s_barrier()
#define LGKM0() asm volatile("s_waitcnt lgkmcnt(0)" ::: "memory")
#define VMC0()  asm volatile("s_waitcnt vmcnt(0)" ::: "memory")

#define STAGE_A(kt, ha, c) do {                                                          \
  gld_lds16(Ag + (size_t)((ha) * 128) * KDIM + (kt) * 64,                                \
            smem + (c) * 32768 + (ha) * 16384 + ldsw);                                   \
  gld_lds16(Ag + (size_t)((ha) * 128 + 64) * KDIM + (kt) * 64,                           \
            smem + (c) * 32768 + (ha) * 16384 + 8192 + ldsw);                            \
} while (0)

#define STAGE_B(kt, hb, c) do {                                                          \
  gld_lds16(Bg + (size_t)((hb) * 128) * KDIM + (kt) * 64,                                \
            smem + 65536 + (c) * 32768 + (hb) * 16384 + ldsw);                           \
  gld_lds16(Bg + (size_t)((hb) * 128 + 64) * KDIM + (kt) * 64,                           \
            smem + 65536 + (c) * 32768 + (hb) * 16384 + 8192 + ldsw);                    \
} while (0)

// 4 B-frag reads for one kk half (COFF = swizzled byte col)
#define READ_B4(DST, c, COFF) do {                                                       \
  const char* _p = smem + 65536 + (c) * 32768 + rowB;                                    \
  _Pragma("unroll")                                                                      \
  for (int n = 0; n < 4; ++n)                                                            \
    DST[n] = *(const bf16x8*)(_p + n * 2048 + (COFF));                                   \
} while (0)

// 8 A-frag reads for one kk half
#define READ_A8(DST, c, COFF) do {                                                       \
  const char* _p = smem + (c) * 32768 + rowA;                                            \
  _Pragma("unroll")                                                                      \
  for (int m16 = 0; m16 < 8; ++m16)                                                      \
    DST[m16] = *(const bf16x8*)(_p + m16 * 2048 + (COFF));                               \
} while (0)

#define MFMA32(AF, BF) do {                                                              \
  __builtin_amdgcn_s_setprio(1);                                                         \
  _Pragma("unroll")                                                                      \
  for (int m16 = 0; m16 < 8; ++m16)                                                      \
    _Pragma("unroll")                                                                    \
    for (int n = 0; n < 4; ++n)                                                          \
      acc[m16][n] = __builtin_amdgcn_mfma_f32_16x16x32_bf16(AF[m16], BF[n],              \
                                                            acc[m16][n], 0, 0, 0);      \
  __builtin_amdgcn_s_setprio(0);                                                         \
} while (0)

// Tile t on buf c. Stage t+1 -> buf c^1 (its readers drained at t-1's LGKM0+BARR).
// Per-wave: read half X (4 B + 8 A), MFMA 32, read half Y, MFMA 32. X/Y swap by
// wave parity. End: LGKM0 retires this tile's reads before t+1 stages buf c;
// VMC0 completes stage(t+1) before BARR releases t+1. Uniform control flow.
#define TILE5(t_, c_, doStage) do {                                                      \
  if (doStage) {                                                                         \
    STAGE_B((t_) + 1, 0, (c_) ^ 1); STAGE_B((t_) + 1, 1, (c_) ^ 1);                      \
    STAGE_A((t_) + 1, 0, (c_) ^ 1); STAGE_A((t_) + 1, 1, (c_) ^ 1);                      \
  }                                                                                      \
  READ_B4(bfrX, c_, coffX); READ_A8(afX, c_, coffX);                                     \
  MFMA32(afX, bfrX);                                                                     \
  READ_B4(bfrY, c_, coffY); READ_A8(afY, c_, coffY);                                     \
  MFMA32(afY, bfrY);                                                                     \
  LGKM0(); VMC0(); BARR();                                                               \
} while (0)

__global__ __launch_bounds__(512, 2) void k_gemm(const unsigned short* __restrict__ A,
                                                 const unsigned short* __restrict__ B,
                                                 const float* __restrict__ bias,
                                                 float* __restrict__ C) {
  __shared__ char smem[131072];   // static 128 KiB
  const int tid  = threadIdx.x;
  const int lane = tid & 63;
  const int wv   = tid >> 6;     // 0..7
  const int wm   = wv >> 2;      // 0..1
  const int wn   = wv & 3;       // 0..3
  const int r    = lane & 15;
  const int q    = lane >> 4;
  const int xr   = r & 7;
  const int coff0 = (q ^ xr) << 4;          // byte col kk=0 (swizzled)
  const int coff1 = ((q + 4) ^ xr) << 4;    // byte col kk=1
  const int coffX = (wv & 1) ? coff1 : coff0;
  const int coffY = (wv & 1) ? coff0 : coff1;
  const int rowA = (wm * 128 + r) * 128;    // byte row base in A tile
  const int rowB = (wn * 64 + r) * 128;     // byte row base in B tile
  const int srow = tid >> 3;                // 0..63 staging row
  const int scol = ((tid & 7) ^ ((tid >> 3) & 7)) * 8;  // pre-swizzled global elem col
  const int ldsw = wv * 1024;               // wave's byte slot per staging call
  const int bm = blockIdx.x;                // 0..31
  const int bn = blockIdx.y;                // 0..15

  const unsigned short* Ag = A + (size_t)(bm * 256 + srow) * KDIM + scol;
  const unsigned short* Bg = B + (size_t)(bn * 256 + srow) * KDIM + scol;

  bf16x8 afX[8], afY[8], bfrX[4], bfrY[4];
  f32x4 acc[8][4];
  #pragma unroll
  for (int m = 0; m < 8; ++m)
    #pragma unroll
    for (int n = 0; n < 4; ++n)
      acc[m][n] = (f32x4){0.f, 0.f, 0.f, 0.f};

  // prologue: stage tile 0 into buf0, wait, one barrier
  STAGE_B(0, 0, 0); STAGE_B(0, 1, 0); STAGE_A(0, 0, 0); STAGE_A(0, 1, 0);
  VMC0();
  BARR();

  #pragma unroll 1
  for (int t = 0; t < 62; t += 2) {
    TILE5(t,     0, 1);
    TILE5(t + 1, 1, 1);
  }
  TILE5(62, 0, 1);
  TILE5(63, 1, 0);

  // ---- epilogue: LDS-repack + coalesced dwordx4 stores (R8-verified) ----
  // eps in A-buf0 [0,32KiB): last buf0 reads at t62 (drained at t62's LGKM0+BARR);
  // last buf0 stage writes issued t61 (drained t61 VMC0). __syncthreads() supplies
  // the compiler-level fence raw s_barrier lacks.
  __syncthreads();
  {
    char* eps = smem + wv * 4096;             // [16 rows][64 f32] per wave
    const int row0 = bm * 256 + wm * 128;
    const int col0 = bn * 256 + wn * 64;
    const f32x4 bias4 = *(const f32x4*)(bias + col0 + r * 4);
    #pragma unroll
    for (int mi = 0; mi < 8; ++mi) {
      #pragma unroll
      for (int j = 0; j < 4; ++j)
        #pragma unroll
        for (int ni = 0; ni < 4; ++ni)
          *(float*)(eps + (((q * 4 + j) * 64) + ni * 16 + r) * 4) = acc[mi][ni][j];
      LGKM0();
      __builtin_amdgcn_sched_barrier(0);
      #pragma unroll
      for (int p = 0; p < 4; ++p) {
        const int row = p * 4 + q;            // 0..15
        f32x4 v = *(const f32x4*)(eps + row * 256 + r * 16);
        v[0] += bias4[0]; v[1] += bias4[1]; v[2] += bias4[2]; v[3] += bias4[3];
        *(f32x4*)(C + (size_t)(row0 + mi * 16 + row) * OUT_F + col0 + r * 4) = v;
      }
      asm volatile("" ::: "memory");          // gather(mi) before scatter(mi+1)
    }
  }
}

extern "C" void kernel_launch(void* const* d_in, const int* in_sizes, int n_in,
                              void* d_out, int out_size, void* d_ws, size_t ws_size,
                              hipStream_t stream) {
  const float* x    = (const float*)d_in[0];
  const int*   idx  = (const int*)d_in[1];
  const float* cb   = (const float*)d_in[2];
  const float* scl  = (const float*)d_in[3];
  const float* lA   = (const float*)d_in[4];
  const float* lB   = (const float*)d_in[5];
  const float* bias = (const float*)d_in[6];
  float* out = (float*)d_out;

  unsigned short* xb = (unsigned short*)d_ws;
  unsigned short* Wc = (unsigned short*)((char*)d_ws + (size_t)M_TOT * KDIM * 2);
  unsigned short* Lbuf = (unsigned short*)d_out;  // bf16 LoRA scratch; overwritten by k_gemm

  k_xcast<<<16384, 256, 0, stream>>>((const f32x4*)x, (u16x8*)xb);
  k_lora<<<dim3(16, 64), 256, 0, stream>>>(lA, lB, Lbuf);
  k_dequant<<<8192, 256, 0, stream>>>(idx, cb, scl, Lbuf, Wc);
  k_gemm<<<dim3(32, 16), 512, 0, stream>>>(xb, Wc, bias, out);
}